// Round 3
// baseline (1606.837 us; speedup 1.0000x reference)
//
#include <hip/hip_runtime.h>
#include <hip/hip_bf16.h>

#define F 64
#define NB 8
#define NE 10
#define GSEG 4
#define EPW 256   // energy-partial spread width (contention relief)

__device__ __forceinline__ float silu(float x) {
    return x / (1.0f + __expf(-x));
}

// wave broadcast: v_readlane -> SGPR, feeds FMA as scalar operand
__device__ __forceinline__ float bcast(float v, int lane) {
    return __uint_as_float(__builtin_amdgcn_readlane(__float_as_uint(v), lane));
}

// ---------------------------------------------------------------------------
// Kernel 1: per-node init. S0[n][g] = attrs[n] @ W_embed; e0 -> epart.
// ---------------------------------------------------------------------------
__global__ __launch_bounds__(256) void init_nodes(
    const float* __restrict__ node_attrs, const float* __restrict__ AE,
    const float* __restrict__ W_embed, const int* __restrict__ batch,
    float* __restrict__ S0, float* __restrict__ epart, int N)
{
    int w = threadIdx.x >> 6, g = threadIdx.x & 63;
    int n = blockIdx.x * 4 + w;
    if (n >= N) return;
    float sc = 0.0f, e0 = 0.0f;
    #pragma unroll
    for (int e = 0; e < NE; e++) {
        float a = node_attrs[n * NE + e];
        sc = fmaf(a, W_embed[e * F + g], sc);
        e0 = fmaf(a, AE[e], e0);
    }
    S0[(size_t)n * F + g] = sc;
    if (g == 0) atomicAdd(&epart[batch[n] * EPW + (n & (EPW - 1))], e0);
}

// ---------------------------------------------------------------------------
// Kernel 2: edge compaction (r < R_MAX) + per-dst degree count.
// ---------------------------------------------------------------------------
__global__ __launch_bounds__(256) void edge_prep(
    const float* __restrict__ pos, const float* __restrict__ shifts,
    const int* __restrict__ EI, int E,
    int* __restrict__ count, float4* __restrict__ geo,
    int* __restrict__ esrc, int* __restrict__ edst, int* __restrict__ deg)
{
    int e = blockIdx.x * 256 + threadIdx.x;
    if (e >= E) return;
    int s = EI[e], d = EI[E + e];
    float vx = pos[d * 3 + 0] - pos[s * 3 + 0] + shifts[e * 3 + 0];
    float vy = pos[d * 3 + 1] - pos[s * 3 + 1] + shifts[e * 3 + 1];
    float vz = pos[d * 3 + 2] - pos[s * 3 + 2] + shifts[e * 3 + 2];
    float len = sqrtf(vx * vx + vy * vy + vz * vz);
    if (len < 5.0f) {
        float ls = (len > 1e-6f) ? len : 1.0f;
        float inv = 1.0f / ls;
        int idx = atomicAdd(count, 1);   // compiler wave-aggregates
        geo[idx] = make_float4(vx * inv, vy * inv, vz * inv, len);
        esrc[idx] = s;
        edst[idx] = d;
        atomicAdd(&deg[d], 1);
    }
}

// ---------------------------------------------------------------------------
// Kernel 3: allocate contiguous CSR ranges (order across nodes irrelevant).
// ---------------------------------------------------------------------------
__global__ __launch_bounds__(256) void alloc_start(
    const int* __restrict__ deg, int* __restrict__ start,
    int* __restrict__ cursor, int* __restrict__ total, int N)
{
    int n = blockIdx.x * 256 + threadIdx.x;
    if (n >= N) return;
    int st = atomicAdd(total, deg[n]);
    start[n] = st;
    cursor[n] = st;
}

// ---------------------------------------------------------------------------
// Kernel 4: scatter compact-edge ids into per-dst CSR slots.
// ---------------------------------------------------------------------------
__global__ __launch_bounds__(256) void scatter_perm(
    const int* __restrict__ count, const int* __restrict__ edst,
    int* __restrict__ cursor, int* __restrict__ perm)
{
    int i = blockIdx.x * 256 + threadIdx.x;
    if (i >= *count) return;
    int p = atomicAdd(&cursor[edst[i]], 1);
    perm[p] = i;
}

// ---------------------------------------------------------------------------
// Kernel 5: fused per-node gather. Block = 512 = 8 waves = 8 nodes.
// Wr1/Wr2 staged once per block into 64 KB LDS (exactly sharedMemPerBlock);
// every cross-lane exchange is a v_readlane broadcast -> no barriers inside
// the per-wave degree loop (waves have different trip counts).
// PHASE 0: write Sout, energy += sc0 @ Wread0
// PHASE 1: residual, energy += silu(sc @ Wm1) @ wm2
// ---------------------------------------------------------------------------
template <int PHASE>
__global__ __launch_bounds__(512, 4) void gather_node(
    const float4* __restrict__ geo, const int* __restrict__ esrc,
    const int* __restrict__ perm, const int* __restrict__ start,
    const int* __restrict__ deg,
    const float* __restrict__ Wr0t, const float* __restrict__ Wr1t,
    const float* __restrict__ Wr2t, const float* __restrict__ Wmixt,
    const float* __restrict__ Wprodt,
    const float* __restrict__ node_attrs, const int* __restrict__ batch,
    const float* __restrict__ Wread0, const float* __restrict__ Wm1,
    const float* __restrict__ wm2,
    const float* __restrict__ Sin, float* __restrict__ Sout,
    float* __restrict__ epart, int N)
{
    __shared__ float Wr1s[4096];    // 16 KB
    __shared__ float Wr2s[12288];   // 48 KB  (total 64 KB)

    int t = threadIdx.x;
    for (int i = t; i < 4096; i += 512)  Wr1s[i] = Wr1t[i];
    for (int i = t; i < 12288; i += 512) Wr2s[i] = Wr2t[i];
    __syncthreads();   // only block-wide barrier; before any divergence

    int g = t & 63;
    int n = blockIdx.x * 8 + (t >> 6);
    if (n >= N) return;

    int st = start[n], dg = deg[n];
    float am0 = 0.f, am1 = 0.f, am2_ = 0.f, am3 = 0.f, am4 = 0.f,
          am5 = 0.f, am6 = 0.f, am7 = 0.f, am8 = 0.f;

    for (int i = 0; i < dg; i++) {
        int e = perm[st + i];
        float4 gv = geo[e];
        int srcn = esrc[e];
        float sv = Sin[(size_t)srcn * F + g];   // overlap with MLP chain
        float ux = gv.x, uy = gv.y, uz = gv.z, r = gv.w;

        // radial embedding
        float rs = fmaxf(r, 1e-6f);
        float s1, c1;
        __sincosf(0.6283185307179586f * rs, &s1, &c1);   // pi*r/5
        float u = r * 0.2f;
        float u2 = u * u, u4 = u2 * u2, u5 = u4 * u, u6 = u5 * u, u7 = u6 * u;
        float fc = 1.0f - 21.0f * u5 + 35.0f * u6 - 15.0f * u7;
        float pref = 0.6324555320336759f / rs * fc;      // sqrt(2/5)
        float ef[NB];
        {
            float sp = 0.0f, sc_ = s1, tc = 2.0f * c1;
            #pragma unroll
            for (int k = 0; k < NB; k++) {
                ef[k] = pref * sc_;
                float sn = tc * sc_ - sp;
                sp = sc_; sc_ = sn;
            }
        }

        // layer 1: 8 -> 64 (Wr0 is 2 KB, L1-hot)
        float a1 = 0.0f;
        #pragma unroll
        for (int k = 0; k < NB; k++) a1 = fmaf(ef[k], Wr0t[k * 64 + g], a1);
        float h1 = silu(a1);

        // layer 2: 64 -> 64, h1 broadcast via readlane, weights from LDS
        float a2 = 0.0f;
        #pragma unroll
        for (int k = 0; k < 64; k++)
            a2 = fmaf(bcast(h1, k), Wr1s[k * 64 + g], a2);
        float h2 = silu(a2);

        // layer 3: 64 -> 192 (lane g computes w[g][0..2]); stride-3 = 2-way ok
        float w0 = 0.f, w1 = 0.f, w2 = 0.f;
        #pragma unroll
        for (int k = 0; k < 64; k++) {
            float hk = bcast(h2, k);
            const float* wr = &Wr2s[k * 192 + g * 3];
            w0 = fmaf(hk, wr[0], w0);
            w1 = fmaf(hk, wr[1], w1);
            w2 = fmaf(hk, wr[2], w2);
        }

        // message accumulate (registers only)
        float m0 = w0 * sv, m1 = w1 * sv, m2 = w2 * sv;
        const float s3 = 1.7320508075688772f;
        const float s5h = 1.1180339887498948f;
        const float s15 = 3.8729833462074170f;
        const float s15h = 1.9364916731037085f;
        am0 += m0;
        am1 = fmaf(m1, s3 * ux, am1);
        am2_ = fmaf(m1, s3 * uy, am2_);
        am3 = fmaf(m1, s3 * uz, am3);
        am4 = fmaf(m2, s15 * ux * uy, am4);
        am5 = fmaf(m2, s15 * uy * uz, am5);
        am6 = fmaf(m2, s5h * (3.0f * uz * uz - 1.0f), am6);
        am7 = fmaf(m2, s15 * ux * uz, am7);
        am8 = fmaf(m2, s15h * (ux * ux - uy * uy), am8);
    }

    const float inv16 = 0.0625f;   // / AVG_NEIGH
    am0 *= inv16; am1 *= inv16; am2_ *= inv16; am3 *= inv16; am4 *= inv16;
    am5 *= inv16; am6 *= inv16; am7 *= inv16; am8 *= inv16;

    // mixing: b[g][s] = sum_f A[f][s] * Wmix[l(s)][f][g] — readlane transpose
    float b0 = 0.f, b1 = 0.f, b2 = 0.f, b3 = 0.f, b4 = 0.f,
          b5 = 0.f, b6 = 0.f, b7 = 0.f, b8 = 0.f;
    #pragma unroll
    for (int f = 0; f < 64; f++) {
        float w0 = Wmixt[f * 64 + g];
        float w1 = Wmixt[4096 + f * 64 + g];
        float w2 = Wmixt[8192 + f * 64 + g];
        b0 = fmaf(bcast(am0, f), w0, b0);
        b1 = fmaf(bcast(am1, f), w1, b1);
        b2 = fmaf(bcast(am2_, f), w1, b2);
        b3 = fmaf(bcast(am3, f), w1, b3);
        b4 = fmaf(bcast(am4, f), w2, b4);
        b5 = fmaf(bcast(am5, f), w2, b5);
        b6 = fmaf(bcast(am6, f), w2, b6);
        b7 = fmaf(bcast(am7, f), w2, b7);
        b8 = fmaf(bcast(am8, f), w2, b8);
    }

    // species-conditioned polynomial scale
    float wp0 = 0.f, wp1 = 0.f, wp2 = 0.f;
    #pragma unroll
    for (int e = 0; e < NE; e++) {
        float a = node_attrs[n * NE + e];
        const float* W = Wprodt + (e * F + g) * 3;
        wp0 = fmaf(a, W[0], wp0);
        wp1 = fmaf(a, W[1], wp1);
        wp2 = fmaf(a, W[2], wp2);
    }
    float p1 = b0;
    float p2 = b0 * b0 + b1 * b1 + b2 * b2 + b3 * b3 + b4 * b4 +
               b5 * b5 + b6 * b6 + b7 * b7 + b8 * b8;
    float scale = wp0 + wp1 * p1 + wp2 * p2;
    float sc0 = b0 * scale;
    int b = batch[n];

    if (PHASE == 0) {
        Sout[(size_t)n * F + g] = sc0;
        float v = sc0 * Wread0[g];
        #pragma unroll
        for (int off = 32; off > 0; off >>= 1) v += __shfl_xor(v, off);
        if (g == 0) atomicAdd(&epart[b * EPW + (n & (EPW - 1))], v);
    } else {
        sc0 += Sin[(size_t)n * F + g];   // residual (prev channel-0)
        // readout: silu(sc @ Wm1) @ wm2 — readlane transpose, no LDS
        int gi = g & 15;
        float acc = 0.0f;
        #pragma unroll
        for (int k = 0; k < 64; k++)
            acc = fmaf(bcast(sc0, k), Wm1[k * 16 + gi], acc);
        float v = (g < 16) ? silu(acc) * wm2[gi] : 0.0f;
        #pragma unroll
        for (int off = 32; off > 0; off >>= 1) v += __shfl_xor(v, off);
        if (g == 0) atomicAdd(&epart[b * EPW + (n & (EPW - 1))], v);
    }
}

// ---------------------------------------------------------------------------
// Kernel 6: final energy reduction; sole writer of d_out.
// ---------------------------------------------------------------------------
__global__ __launch_bounds__(256) void reduce_energy(
    const float* __restrict__ epart, float* __restrict__ out)
{
    int t = threadIdx.x;
    __shared__ float ps[GSEG][4];
    for (int b = 0; b < GSEG; b++) {
        float v = epart[b * EPW + t];
        #pragma unroll
        for (int off = 32; off > 0; off >>= 1) v += __shfl_xor(v, off);
        if ((t & 63) == 0) ps[b][t >> 6] = v;
    }
    __syncthreads();
    if (t < GSEG) out[t] = ps[t][0] + ps[t][1] + ps[t][2] + ps[t][3];
}

extern "C" void kernel_launch(void* const* d_in, const int* in_sizes, int n_in,
                              void* d_out, int out_size, void* d_ws, size_t ws_size,
                              hipStream_t stream) {
    const float* positions  = (const float*)d_in[0];
    const float* node_attrs = (const float*)d_in[1];
    const float* shifts     = (const float*)d_in[2];
    // d_in[3] charges: unused (charge_density never feeds energy)
    const int*   edge_index = (const int*)d_in[4];
    const int*   batch      = (const int*)d_in[5];
    const float* AE         = (const float*)d_in[6];
    const float* W_embed    = (const float*)d_in[7];
    const float* Wr0        = (const float*)d_in[8];
    const float* Wr1        = (const float*)d_in[9];
    const float* Wr2        = (const float*)d_in[10];
    const float* Wmix       = (const float*)d_in[11];
    const float* Wprod      = (const float*)d_in[12];
    const float* Wread0     = (const float*)d_in[13];
    const float* Wm1        = (const float*)d_in[14];
    const float* wm2        = (const float*)d_in[15];
    // d_in[16] Wq: unused

    int N = in_sizes[0] / 3;
    int E = in_sizes[4] / 2;
    float* out = (float*)d_out;

    char* ws = (char*)d_ws;
    size_t off = 0;
    float4* geo   = (float4*)(ws + off); off += (size_t)E * sizeof(float4);
    float*  S0    = (float*)(ws + off);  off += (size_t)N * F * sizeof(float);
    float*  S1    = (float*)(ws + off);  off += (size_t)N * F * sizeof(float);
    int*    esrc  = (int*)(ws + off);    off += (size_t)E * sizeof(int);
    int*    edst  = (int*)(ws + off);    off += (size_t)E * sizeof(int);
    int*    perm  = (int*)(ws + off);    off += (size_t)E * sizeof(int);
    int*    deg   = (int*)(ws + off);    off += (size_t)N * sizeof(int);
    int*    start = (int*)(ws + off);    off += (size_t)N * sizeof(int);
    int*    cursor= (int*)(ws + off);    off += (size_t)N * sizeof(int);
    float*  epart = (float*)(ws + off);  off += GSEG * EPW * sizeof(float);
    int*    count = (int*)(ws + off);    off += 128;
    int*    total = (int*)(ws + off);    off += 128;

    hipMemsetAsync(deg, 0, (size_t)N * sizeof(int), stream);
    hipMemsetAsync(epart, 0, GSEG * EPW * sizeof(float) + 256, stream); // + count/total

    int nodeBlocks4 = (N + 3) / 4;
    int nodeBlocks256 = (N + 255) / 256;
    int edgeBlocks = (E + 255) / 256;
    int gatherBlocks = (N + 7) / 8;

    init_nodes<<<nodeBlocks4, 256, 0, stream>>>(node_attrs, AE, W_embed, batch, S0, epart, N);
    edge_prep<<<edgeBlocks, 256, 0, stream>>>(positions, shifts, edge_index, E,
                                              count, geo, esrc, edst, deg);
    alloc_start<<<nodeBlocks256, 256, 0, stream>>>(deg, start, cursor, total, N);
    scatter_perm<<<edgeBlocks, 256, 0, stream>>>(count, edst, cursor, perm);

    // t = 0: read S0, write S1
    gather_node<0><<<gatherBlocks, 512, 0, stream>>>(geo, esrc, perm, start, deg,
                                         Wr0, Wr1, Wr2, Wmix, Wprod,
                                         node_attrs, batch, Wread0, Wm1, wm2,
                                         S0, S1, epart, N);
    // t = 1: read S1 (messages + residual), no Sout needed
    gather_node<1><<<gatherBlocks, 512, 0, stream>>>(geo, esrc, perm, start, deg,
                                         Wr0 + 512, Wr1 + 4096, Wr2 + 12288,
                                         Wmix + 12288, Wprod + NE * F * 3,
                                         node_attrs, batch, Wread0, Wm1, wm2,
                                         S1, S1, epart, N);

    reduce_energy<<<1, 256, 0, stream>>>(epart, out);
}

// Round 4
// 861.506 us; speedup vs baseline: 1.8651x; 1.8651x over previous
//
#include <hip/hip_runtime.h>
#include <hip/hip_bf16.h>

#define F 64
#define NB 8
#define NE 10
#define GSEG 4
#define EPW 256   // energy-partial spread width (contention relief)

__device__ __forceinline__ float silu(float x) {
    return x / (1.0f + __expf(-x));
}

// wave broadcast: v_readlane -> SGPR, feeds FMA as scalar operand
__device__ __forceinline__ float bcast(float v, int lane) {
    return __uint_as_float(__builtin_amdgcn_readlane(__float_as_uint(v), lane));
}

// ---------------------------------------------------------------------------
// Kernel 1: per-node init. S0[n][g] = attrs[n] @ W_embed; e0 -> epart.
// ---------------------------------------------------------------------------
__global__ __launch_bounds__(256) void init_nodes(
    const float* __restrict__ node_attrs, const float* __restrict__ AE,
    const float* __restrict__ W_embed, const int* __restrict__ batch,
    float* __restrict__ S0, float* __restrict__ epart, int N)
{
    int w = threadIdx.x >> 6, g = threadIdx.x & 63;
    int n = blockIdx.x * 4 + w;
    if (n >= N) return;
    float sc = 0.0f, e0 = 0.0f;
    #pragma unroll
    for (int e = 0; e < NE; e++) {
        float a = node_attrs[n * NE + e];
        sc = fmaf(a, W_embed[e * F + g], sc);
        e0 = fmaf(a, AE[e], e0);
    }
    S0[(size_t)n * F + g] = sc;
    if (g == 0) atomicAdd(&epart[batch[n] * EPW + (n & (EPW - 1))], e0);
}

// ---------------------------------------------------------------------------
// Kernel 2: edge compaction (r < R_MAX) + per-dst degree count.
// ---------------------------------------------------------------------------
__global__ __launch_bounds__(256) void edge_prep(
    const float* __restrict__ pos, const float* __restrict__ shifts,
    const int* __restrict__ EI, int E,
    int* __restrict__ count, float4* __restrict__ geo,
    int* __restrict__ esrc, int* __restrict__ edst, int* __restrict__ deg)
{
    int e = blockIdx.x * 256 + threadIdx.x;
    if (e >= E) return;
    int s = EI[e], d = EI[E + e];
    float vx = pos[d * 3 + 0] - pos[s * 3 + 0] + shifts[e * 3 + 0];
    float vy = pos[d * 3 + 1] - pos[s * 3 + 1] + shifts[e * 3 + 1];
    float vz = pos[d * 3 + 2] - pos[s * 3 + 2] + shifts[e * 3 + 2];
    float len = sqrtf(vx * vx + vy * vy + vz * vz);
    if (len < 5.0f) {
        float ls = (len > 1e-6f) ? len : 1.0f;
        float inv = 1.0f / ls;
        int idx = atomicAdd(count, 1);   // compiler wave-aggregates
        geo[idx] = make_float4(vx * inv, vy * inv, vz * inv, len);
        esrc[idx] = s;
        edst[idx] = d;
        atomicAdd(&deg[d], 1);
    }
}

// ---------------------------------------------------------------------------
// Kernel 3: allocate contiguous CSR ranges (order across nodes irrelevant).
// ---------------------------------------------------------------------------
__global__ __launch_bounds__(256) void alloc_start(
    const int* __restrict__ deg, int* __restrict__ start,
    int* __restrict__ cursor, int* __restrict__ total, int N)
{
    int n = blockIdx.x * 256 + threadIdx.x;
    if (n >= N) return;
    int st = atomicAdd(total, deg[n]);
    start[n] = st;
    cursor[n] = st;
}

// ---------------------------------------------------------------------------
// Kernel 4: scatter compact-edge ids into per-dst CSR slots.
// ---------------------------------------------------------------------------
__global__ __launch_bounds__(256) void scatter_perm(
    const int* __restrict__ count, const int* __restrict__ edst,
    int* __restrict__ cursor, int* __restrict__ perm)
{
    int i = blockIdx.x * 256 + threadIdx.x;
    if (i >= *count) return;
    int p = atomicAdd(&cursor[edst[i]], 1);
    perm[p] = i;
}

// ---------------------------------------------------------------------------
// Kernel 5: fused per-node gather. Block = 512 = 8 waves = 8 nodes.
// Wr1/Wr2 staged once per block into 64 KB LDS; all cross-lane exchange via
// v_readlane broadcast -> no barriers inside the per-wave degree loop.
// NOTE: no min-waves in __launch_bounds__ — round 3's (512,4) capped VGPR at
// 64 and spilled the per-edge loop to scratch (1.28 GB HBM/dispatch).
// PHASE 0: write Sout, energy += sc0 @ Wread0
// PHASE 1: residual, energy += silu(sc @ Wm1) @ wm2
// ---------------------------------------------------------------------------
template <int PHASE>
__global__ __launch_bounds__(512) void gather_node(
    const float4* __restrict__ geo, const int* __restrict__ esrc,
    const int* __restrict__ perm, const int* __restrict__ start,
    const int* __restrict__ deg,
    const float* __restrict__ Wr0t, const float* __restrict__ Wr1t,
    const float* __restrict__ Wr2t, const float* __restrict__ Wmixt,
    const float* __restrict__ Wprodt,
    const float* __restrict__ node_attrs, const int* __restrict__ batch,
    const float* __restrict__ Wread0, const float* __restrict__ Wm1,
    const float* __restrict__ wm2,
    const float* __restrict__ Sin, float* __restrict__ Sout,
    float* __restrict__ epart, int N)
{
    __shared__ float Wr1s[4096];    // 16 KB
    __shared__ float Wr2s[12288];   // 48 KB  (total 64 KB -> 2 blocks/CU)

    int t = threadIdx.x;
    for (int i = t; i < 4096; i += 512)  Wr1s[i] = Wr1t[i];
    for (int i = t; i < 12288; i += 512) Wr2s[i] = Wr2t[i];
    __syncthreads();   // only block-wide barrier; before any divergence

    int g = t & 63;
    int n = blockIdx.x * 8 + (t >> 6);
    if (n >= N) return;

    int st = start[n], dg = deg[n];
    float am0 = 0.f, am1 = 0.f, am2_ = 0.f, am3 = 0.f, am4 = 0.f,
          am5 = 0.f, am6 = 0.f, am7 = 0.f, am8 = 0.f;

    for (int i = 0; i < dg; i++) {
        int e = perm[st + i];
        float4 gv = geo[e];
        int srcn = esrc[e];
        float sv = Sin[(size_t)srcn * F + g];   // overlap with MLP chain
        float ux = gv.x, uy = gv.y, uz = gv.z, r = gv.w;

        // radial embedding
        float rs = fmaxf(r, 1e-6f);
        float s1, c1;
        __sincosf(0.6283185307179586f * rs, &s1, &c1);   // pi*r/5
        float u = r * 0.2f;
        float u2 = u * u, u4 = u2 * u2, u5 = u4 * u, u6 = u5 * u, u7 = u6 * u;
        float fc = 1.0f - 21.0f * u5 + 35.0f * u6 - 15.0f * u7;
        float pref = 0.6324555320336759f / rs * fc;      // sqrt(2/5)
        float ef[NB];
        {
            float sp = 0.0f, sc_ = s1, tc = 2.0f * c1;
            #pragma unroll
            for (int k = 0; k < NB; k++) {
                ef[k] = pref * sc_;
                float sn = tc * sc_ - sp;
                sp = sc_; sc_ = sn;
            }
        }

        // layer 1: 8 -> 64 (Wr0 is 2 KB, L1-hot)
        float a1 = 0.0f;
        #pragma unroll
        for (int k = 0; k < NB; k++) a1 = fmaf(ef[k], Wr0t[k * 64 + g], a1);
        float h1 = silu(a1);

        // layer 2: 64 -> 64, h1 broadcast via readlane, weights from LDS
        float a2 = 0.0f;
        #pragma unroll
        for (int k = 0; k < 64; k++)
            a2 = fmaf(bcast(h1, k), Wr1s[k * 64 + g], a2);
        float h2 = silu(a2);

        // layer 3: 64 -> 192 (lane g computes w[g][0..2]); stride-3 = 2-way ok
        float w0 = 0.f, w1 = 0.f, w2 = 0.f;
        #pragma unroll
        for (int k = 0; k < 64; k++) {
            float hk = bcast(h2, k);
            const float* wr = &Wr2s[k * 192 + g * 3];
            w0 = fmaf(hk, wr[0], w0);
            w1 = fmaf(hk, wr[1], w1);
            w2 = fmaf(hk, wr[2], w2);
        }

        // message accumulate (registers only)
        float m0 = w0 * sv, m1 = w1 * sv, m2 = w2 * sv;
        const float s3 = 1.7320508075688772f;
        const float s5h = 1.1180339887498948f;
        const float s15 = 3.8729833462074170f;
        const float s15h = 1.9364916731037085f;
        am0 += m0;
        am1 = fmaf(m1, s3 * ux, am1);
        am2_ = fmaf(m1, s3 * uy, am2_);
        am3 = fmaf(m1, s3 * uz, am3);
        am4 = fmaf(m2, s15 * ux * uy, am4);
        am5 = fmaf(m2, s15 * uy * uz, am5);
        am6 = fmaf(m2, s5h * (3.0f * uz * uz - 1.0f), am6);
        am7 = fmaf(m2, s15 * ux * uz, am7);
        am8 = fmaf(m2, s15h * (ux * ux - uy * uy), am8);
    }

    const float inv16 = 0.0625f;   // / AVG_NEIGH
    am0 *= inv16; am1 *= inv16; am2_ *= inv16; am3 *= inv16; am4 *= inv16;
    am5 *= inv16; am6 *= inv16; am7 *= inv16; am8 *= inv16;

    // mixing: b[g][s] = sum_f A[f][s] * Wmix[l(s)][f][g] — readlane transpose
    float b0 = 0.f, b1 = 0.f, b2 = 0.f, b3 = 0.f, b4 = 0.f,
          b5 = 0.f, b6 = 0.f, b7 = 0.f, b8 = 0.f;
    #pragma unroll
    for (int f = 0; f < 64; f++) {
        float w0 = Wmixt[f * 64 + g];
        float w1 = Wmixt[4096 + f * 64 + g];
        float w2 = Wmixt[8192 + f * 64 + g];
        b0 = fmaf(bcast(am0, f), w0, b0);
        b1 = fmaf(bcast(am1, f), w1, b1);
        b2 = fmaf(bcast(am2_, f), w1, b2);
        b3 = fmaf(bcast(am3, f), w1, b3);
        b4 = fmaf(bcast(am4, f), w2, b4);
        b5 = fmaf(bcast(am5, f), w2, b5);
        b6 = fmaf(bcast(am6, f), w2, b6);
        b7 = fmaf(bcast(am7, f), w2, b7);
        b8 = fmaf(bcast(am8, f), w2, b8);
    }

    // species-conditioned polynomial scale
    float wp0 = 0.f, wp1 = 0.f, wp2 = 0.f;
    #pragma unroll
    for (int e = 0; e < NE; e++) {
        float a = node_attrs[n * NE + e];
        const float* W = Wprodt + (e * F + g) * 3;
        wp0 = fmaf(a, W[0], wp0);
        wp1 = fmaf(a, W[1], wp1);
        wp2 = fmaf(a, W[2], wp2);
    }
    float p1 = b0;
    float p2 = b0 * b0 + b1 * b1 + b2 * b2 + b3 * b3 + b4 * b4 +
               b5 * b5 + b6 * b6 + b7 * b7 + b8 * b8;
    float scale = wp0 + wp1 * p1 + wp2 * p2;
    float sc0 = b0 * scale;
    int b = batch[n];

    if (PHASE == 0) {
        Sout[(size_t)n * F + g] = sc0;
        float v = sc0 * Wread0[g];
        #pragma unroll
        for (int off = 32; off > 0; off >>= 1) v += __shfl_xor(v, off);
        if (g == 0) atomicAdd(&epart[b * EPW + (n & (EPW - 1))], v);
    } else {
        sc0 += Sin[(size_t)n * F + g];   // residual (prev channel-0)
        // readout: silu(sc @ Wm1) @ wm2 — readlane transpose, no LDS
        int gi = g & 15;
        float acc = 0.0f;
        #pragma unroll
        for (int k = 0; k < 64; k++)
            acc = fmaf(bcast(sc0, k), Wm1[k * 16 + gi], acc);
        float v = (g < 16) ? silu(acc) * wm2[gi] : 0.0f;
        #pragma unroll
        for (int off = 32; off > 0; off >>= 1) v += __shfl_xor(v, off);
        if (g == 0) atomicAdd(&epart[b * EPW + (n & (EPW - 1))], v);
    }
}

// ---------------------------------------------------------------------------
// Kernel 6: final energy reduction; sole writer of d_out.
// ---------------------------------------------------------------------------
__global__ __launch_bounds__(256) void reduce_energy(
    const float* __restrict__ epart, float* __restrict__ out)
{
    int t = threadIdx.x;
    __shared__ float ps[GSEG][4];
    for (int b = 0; b < GSEG; b++) {
        float v = epart[b * EPW + t];
        #pragma unroll
        for (int off = 32; off > 0; off >>= 1) v += __shfl_xor(v, off);
        if ((t & 63) == 0) ps[b][t >> 6] = v;
    }
    __syncthreads();
    if (t < GSEG) out[t] = ps[t][0] + ps[t][1] + ps[t][2] + ps[t][3];
}

extern "C" void kernel_launch(void* const* d_in, const int* in_sizes, int n_in,
                              void* d_out, int out_size, void* d_ws, size_t ws_size,
                              hipStream_t stream) {
    const float* positions  = (const float*)d_in[0];
    const float* node_attrs = (const float*)d_in[1];
    const float* shifts     = (const float*)d_in[2];
    // d_in[3] charges: unused (charge_density never feeds energy)
    const int*   edge_index = (const int*)d_in[4];
    const int*   batch      = (const int*)d_in[5];
    const float* AE         = (const float*)d_in[6];
    const float* W_embed    = (const float*)d_in[7];
    const float* Wr0        = (const float*)d_in[8];
    const float* Wr1        = (const float*)d_in[9];
    const float* Wr2        = (const float*)d_in[10];
    const float* Wmix       = (const float*)d_in[11];
    const float* Wprod      = (const float*)d_in[12];
    const float* Wread0     = (const float*)d_in[13];
    const float* Wm1        = (const float*)d_in[14];
    const float* wm2        = (const float*)d_in[15];
    // d_in[16] Wq: unused

    int N = in_sizes[0] / 3;
    int E = in_sizes[4] / 2;
    float* out = (float*)d_out;

    char* ws = (char*)d_ws;
    size_t off = 0;
    float4* geo   = (float4*)(ws + off); off += (size_t)E * sizeof(float4);
    float*  S0    = (float*)(ws + off);  off += (size_t)N * F * sizeof(float);
    float*  S1    = (float*)(ws + off);  off += (size_t)N * F * sizeof(float);
    int*    esrc  = (int*)(ws + off);    off += (size_t)E * sizeof(int);
    int*    edst  = (int*)(ws + off);    off += (size_t)E * sizeof(int);
    int*    perm  = (int*)(ws + off);    off += (size_t)E * sizeof(int);
    int*    deg   = (int*)(ws + off);    off += (size_t)N * sizeof(int);
    int*    start = (int*)(ws + off);    off += (size_t)N * sizeof(int);
    int*    cursor= (int*)(ws + off);    off += (size_t)N * sizeof(int);
    float*  epart = (float*)(ws + off);  off += GSEG * EPW * sizeof(float);
    int*    count = (int*)(ws + off);    off += 128;
    int*    total = (int*)(ws + off);    off += 128;

    hipMemsetAsync(deg, 0, (size_t)N * sizeof(int), stream);
    hipMemsetAsync(epart, 0, GSEG * EPW * sizeof(float) + 256, stream); // + count/total

    int nodeBlocks4 = (N + 3) / 4;
    int nodeBlocks256 = (N + 255) / 256;
    int edgeBlocks = (E + 255) / 256;
    int gatherBlocks = (N + 7) / 8;

    init_nodes<<<nodeBlocks4, 256, 0, stream>>>(node_attrs, AE, W_embed, batch, S0, epart, N);
    edge_prep<<<edgeBlocks, 256, 0, stream>>>(positions, shifts, edge_index, E,
                                              count, geo, esrc, edst, deg);
    alloc_start<<<nodeBlocks256, 256, 0, stream>>>(deg, start, cursor, total, N);
    scatter_perm<<<edgeBlocks, 256, 0, stream>>>(count, edst, cursor, perm);

    // t = 0: read S0, write S1
    gather_node<0><<<gatherBlocks, 512, 0, stream>>>(geo, esrc, perm, start, deg,
                                         Wr0, Wr1, Wr2, Wmix, Wprod,
                                         node_attrs, batch, Wread0, Wm1, wm2,
                                         S0, S1, epart, N);
    // t = 1: read S1 (messages + residual), no Sout needed
    gather_node<1><<<gatherBlocks, 512, 0, stream>>>(geo, esrc, perm, start, deg,
                                         Wr0 + 512, Wr1 + 4096, Wr2 + 12288,
                                         Wmix + 12288, Wprod + NE * F * 3,
                                         node_attrs, batch, Wread0, Wm1, wm2,
                                         S1, S1, epart, N);

    reduce_energy<<<1, 256, 0, stream>>>(epart, out);
}

// Round 5
// 858.823 us; speedup vs baseline: 1.8710x; 1.0031x over previous
//
#include <hip/hip_runtime.h>
#include <hip/hip_bf16.h>

#define F 64
#define NB 8
#define NE 10
#define GSEG 4
#define EPW 256   // energy-partial spread width (contention relief)

__device__ __forceinline__ float silu(float x) {
    return x / (1.0f + __expf(-x));
}

// wave broadcast: v_readlane -> SGPR, feeds FMA as scalar operand
__device__ __forceinline__ float bcast(float v, int lane) {
    return __uint_as_float(__builtin_amdgcn_readlane(__float_as_uint(v), lane));
}

// ---------------------------------------------------------------------------
// Kernel 1: per-node init. S0[n][g] = attrs[n] @ W_embed; e0 -> epart.
// ---------------------------------------------------------------------------
__global__ __launch_bounds__(256) void init_nodes(
    const float* __restrict__ node_attrs, const float* __restrict__ AE,
    const float* __restrict__ W_embed, const int* __restrict__ batch,
    float* __restrict__ S0, float* __restrict__ epart, int N)
{
    int w = threadIdx.x >> 6, g = threadIdx.x & 63;
    int n = blockIdx.x * 4 + w;
    if (n >= N) return;
    float sc = 0.0f, e0 = 0.0f;
    #pragma unroll
    for (int e = 0; e < NE; e++) {
        float a = node_attrs[n * NE + e];
        sc = fmaf(a, W_embed[e * F + g], sc);
        e0 = fmaf(a, AE[e], e0);
    }
    S0[(size_t)n * F + g] = sc;
    if (g == 0) atomicAdd(&epart[batch[n] * EPW + (n & (EPW - 1))], e0);
}

// ---------------------------------------------------------------------------
// Kernel 2: edge compaction (r < R_MAX) + per-dst degree count.
// ---------------------------------------------------------------------------
__global__ __launch_bounds__(256) void edge_prep(
    const float* __restrict__ pos, const float* __restrict__ shifts,
    const int* __restrict__ EI, int E,
    int* __restrict__ count, float4* __restrict__ geo,
    int* __restrict__ esrc, int* __restrict__ edst, int* __restrict__ deg)
{
    int e = blockIdx.x * 256 + threadIdx.x;
    if (e >= E) return;
    int s = EI[e], d = EI[E + e];
    float vx = pos[d * 3 + 0] - pos[s * 3 + 0] + shifts[e * 3 + 0];
    float vy = pos[d * 3 + 1] - pos[s * 3 + 1] + shifts[e * 3 + 1];
    float vz = pos[d * 3 + 2] - pos[s * 3 + 2] + shifts[e * 3 + 2];
    float len = sqrtf(vx * vx + vy * vy + vz * vz);
    if (len < 5.0f) {
        float ls = (len > 1e-6f) ? len : 1.0f;
        float inv = 1.0f / ls;
        int idx = atomicAdd(count, 1);   // compiler wave-aggregates
        geo[idx] = make_float4(vx * inv, vy * inv, vz * inv, len);
        esrc[idx] = s;
        edst[idx] = d;
        atomicAdd(&deg[d], 1);
    }
}

// ---------------------------------------------------------------------------
// Kernel 3: allocate contiguous CSR ranges (order across nodes irrelevant).
// ---------------------------------------------------------------------------
__global__ __launch_bounds__(256) void alloc_start(
    const int* __restrict__ deg, int* __restrict__ start,
    int* __restrict__ cursor, int* __restrict__ total, int N)
{
    int n = blockIdx.x * 256 + threadIdx.x;
    if (n >= N) return;
    int st = atomicAdd(total, deg[n]);
    start[n] = st;
    cursor[n] = st;
}

// ---------------------------------------------------------------------------
// Kernel 4: place geometry + src id DIRECTLY into CSR slots (no perm
// indirection in the hot gather loop).
// ---------------------------------------------------------------------------
__global__ __launch_bounds__(256) void csr_fill(
    const int* __restrict__ count, const float4* __restrict__ geo,
    const int* __restrict__ esrc, const int* __restrict__ edst,
    int* __restrict__ cursor,
    float4* __restrict__ geoS, int* __restrict__ srcS)
{
    int i = blockIdx.x * 256 + threadIdx.x;
    if (i >= *count) return;
    int p = atomicAdd(&cursor[edst[i]], 1);
    geoS[p] = geo[i];
    srcS[p] = esrc[i];
}

// ---------------------------------------------------------------------------
// Kernel 5: fused per-node gather. Block = 512 = 8 waves = 8 nodes.
// Wr1/Wr2 staged once per block into 64 KB LDS; cross-lane via v_readlane.
// __launch_bounds__(512, 2): min 2 waves/SIMD -> 256-VGPR budget. Round 4's
// default heuristic picked 128 VGPR (targeting 2 blocks/CU) and spilled the
// per-edge loop to scratch (187 MB HBM writes/dispatch). Natural ~160 VGPR.
// PHASE 0: write Sout, energy += sc0 @ Wread0
// PHASE 1: residual, energy += silu(sc @ Wm1) @ wm2
// ---------------------------------------------------------------------------
template <int PHASE>
__global__ __launch_bounds__(512, 2) void gather_node(
    const float4* __restrict__ geoS, const int* __restrict__ srcS,
    const int* __restrict__ start, const int* __restrict__ deg,
    const float* __restrict__ Wr0t, const float* __restrict__ Wr1t,
    const float* __restrict__ Wr2t, const float* __restrict__ Wmixt,
    const float* __restrict__ Wprodt,
    const float* __restrict__ node_attrs, const int* __restrict__ batch,
    const float* __restrict__ Wread0, const float* __restrict__ Wm1,
    const float* __restrict__ wm2,
    const float* __restrict__ Sin, float* __restrict__ Sout,
    float* __restrict__ epart, int N)
{
    __shared__ float Wr1s[4096];    // 16 KB
    __shared__ float Wr2s[12288];   // 48 KB  (total 64 KB)

    int t = threadIdx.x;
    for (int i = t; i < 4096; i += 512)  Wr1s[i] = Wr1t[i];
    for (int i = t; i < 12288; i += 512) Wr2s[i] = Wr2t[i];
    __syncthreads();   // only block-wide barrier; before any divergence

    int g = t & 63;
    int n = blockIdx.x * 8 + (t >> 6);
    if (n >= N) return;

    int st = start[n], dg = deg[n];
    float am0 = 0.f, am1 = 0.f, am2_ = 0.f, am3 = 0.f, am4 = 0.f,
          am5 = 0.f, am6 = 0.f, am7 = 0.f, am8 = 0.f;

    for (int i = 0; i < dg; i++) {
        float4 gv = geoS[st + i];    // sequential, no indirection
        int srcn = srcS[st + i];
        float sv = Sin[(size_t)srcn * F + g];   // overlap with MLP chain
        float ux = gv.x, uy = gv.y, uz = gv.z, r = gv.w;

        // radial embedding
        float rs = fmaxf(r, 1e-6f);
        float s1, c1;
        __sincosf(0.6283185307179586f * rs, &s1, &c1);   // pi*r/5
        float u = r * 0.2f;
        float u2 = u * u, u4 = u2 * u2, u5 = u4 * u, u6 = u5 * u, u7 = u6 * u;
        float fc = 1.0f - 21.0f * u5 + 35.0f * u6 - 15.0f * u7;
        float pref = 0.6324555320336759f / rs * fc;      // sqrt(2/5)
        float ef[NB];
        {
            float sp = 0.0f, sc_ = s1, tc = 2.0f * c1;
            #pragma unroll
            for (int k = 0; k < NB; k++) {
                ef[k] = pref * sc_;
                float sn = tc * sc_ - sp;
                sp = sc_; sc_ = sn;
            }
        }

        // layer 1: 8 -> 64 (Wr0 is 2 KB, L1-hot)
        float a1 = 0.0f;
        #pragma unroll
        for (int k = 0; k < NB; k++) a1 = fmaf(ef[k], Wr0t[k * 64 + g], a1);
        float h1 = silu(a1);

        // layer 2: 64 -> 64, h1 broadcast via readlane, weights from LDS
        float a2 = 0.0f;
        #pragma unroll
        for (int k = 0; k < 64; k++)
            a2 = fmaf(bcast(h1, k), Wr1s[k * 64 + g], a2);
        float h2 = silu(a2);

        // layer 3: 64 -> 192 (lane g computes w[g][0..2]); stride-3 = 2-way ok
        float w0 = 0.f, w1 = 0.f, w2 = 0.f;
        #pragma unroll
        for (int k = 0; k < 64; k++) {
            float hk = bcast(h2, k);
            const float* wr = &Wr2s[k * 192 + g * 3];
            w0 = fmaf(hk, wr[0], w0);
            w1 = fmaf(hk, wr[1], w1);
            w2 = fmaf(hk, wr[2], w2);
        }

        // message accumulate (registers only)
        float m0 = w0 * sv, m1 = w1 * sv, m2 = w2 * sv;
        const float s3 = 1.7320508075688772f;
        const float s5h = 1.1180339887498948f;
        const float s15 = 3.8729833462074170f;
        const float s15h = 1.9364916731037085f;
        am0 += m0;
        am1 = fmaf(m1, s3 * ux, am1);
        am2_ = fmaf(m1, s3 * uy, am2_);
        am3 = fmaf(m1, s3 * uz, am3);
        am4 = fmaf(m2, s15 * ux * uy, am4);
        am5 = fmaf(m2, s15 * uy * uz, am5);
        am6 = fmaf(m2, s5h * (3.0f * uz * uz - 1.0f), am6);
        am7 = fmaf(m2, s15 * ux * uz, am7);
        am8 = fmaf(m2, s15h * (ux * ux - uy * uy), am8);
    }

    const float inv16 = 0.0625f;   // / AVG_NEIGH
    am0 *= inv16; am1 *= inv16; am2_ *= inv16; am3 *= inv16; am4 *= inv16;
    am5 *= inv16; am6 *= inv16; am7 *= inv16; am8 *= inv16;

    // mixing: b[g][s] = sum_f A[f][s] * Wmix[l(s)][f][g] — readlane transpose
    float b0 = 0.f, b1 = 0.f, b2 = 0.f, b3 = 0.f, b4 = 0.f,
          b5 = 0.f, b6 = 0.f, b7 = 0.f, b8 = 0.f;
    #pragma unroll
    for (int f = 0; f < 64; f++) {
        float w0 = Wmixt[f * 64 + g];
        float w1 = Wmixt[4096 + f * 64 + g];
        float w2 = Wmixt[8192 + f * 64 + g];
        b0 = fmaf(bcast(am0, f), w0, b0);
        b1 = fmaf(bcast(am1, f), w1, b1);
        b2 = fmaf(bcast(am2_, f), w1, b2);
        b3 = fmaf(bcast(am3, f), w1, b3);
        b4 = fmaf(bcast(am4, f), w2, b4);
        b5 = fmaf(bcast(am5, f), w2, b5);
        b6 = fmaf(bcast(am6, f), w2, b6);
        b7 = fmaf(bcast(am7, f), w2, b7);
        b8 = fmaf(bcast(am8, f), w2, b8);
    }

    // species-conditioned polynomial scale
    float wp0 = 0.f, wp1 = 0.f, wp2 = 0.f;
    #pragma unroll
    for (int e = 0; e < NE; e++) {
        float a = node_attrs[n * NE + e];
        const float* W = Wprodt + (e * F + g) * 3;
        wp0 = fmaf(a, W[0], wp0);
        wp1 = fmaf(a, W[1], wp1);
        wp2 = fmaf(a, W[2], wp2);
    }
    float p1 = b0;
    float p2 = b0 * b0 + b1 * b1 + b2 * b2 + b3 * b3 + b4 * b4 +
               b5 * b5 + b6 * b6 + b7 * b7 + b8 * b8;
    float scale = wp0 + wp1 * p1 + wp2 * p2;
    float sc0 = b0 * scale;
    int b = batch[n];

    if (PHASE == 0) {
        Sout[(size_t)n * F + g] = sc0;
        float v = sc0 * Wread0[g];
        #pragma unroll
        for (int off = 32; off > 0; off >>= 1) v += __shfl_xor(v, off);
        if (g == 0) atomicAdd(&epart[b * EPW + (n & (EPW - 1))], v);
    } else {
        sc0 += Sin[(size_t)n * F + g];   // residual (prev channel-0)
        // readout: silu(sc @ Wm1) @ wm2 — readlane transpose, no LDS
        int gi = g & 15;
        float acc = 0.0f;
        #pragma unroll
        for (int k = 0; k < 64; k++)
            acc = fmaf(bcast(sc0, k), Wm1[k * 16 + gi], acc);
        float v = (g < 16) ? silu(acc) * wm2[gi] : 0.0f;
        #pragma unroll
        for (int off = 32; off > 0; off >>= 1) v += __shfl_xor(v, off);
        if (g == 0) atomicAdd(&epart[b * EPW + (n & (EPW - 1))], v);
    }
}

// ---------------------------------------------------------------------------
// Kernel 6: final energy reduction; sole writer of d_out.
// ---------------------------------------------------------------------------
__global__ __launch_bounds__(256) void reduce_energy(
    const float* __restrict__ epart, float* __restrict__ out)
{
    int t = threadIdx.x;
    __shared__ float ps[GSEG][4];
    for (int b = 0; b < GSEG; b++) {
        float v = epart[b * EPW + t];
        #pragma unroll
        for (int off = 32; off > 0; off >>= 1) v += __shfl_xor(v, off);
        if ((t & 63) == 0) ps[b][t >> 6] = v;
    }
    __syncthreads();
    if (t < GSEG) out[t] = ps[t][0] + ps[t][1] + ps[t][2] + ps[t][3];
}

extern "C" void kernel_launch(void* const* d_in, const int* in_sizes, int n_in,
                              void* d_out, int out_size, void* d_ws, size_t ws_size,
                              hipStream_t stream) {
    const float* positions  = (const float*)d_in[0];
    const float* node_attrs = (const float*)d_in[1];
    const float* shifts     = (const float*)d_in[2];
    // d_in[3] charges: unused (charge_density never feeds energy)
    const int*   edge_index = (const int*)d_in[4];
    const int*   batch      = (const int*)d_in[5];
    const float* AE         = (const float*)d_in[6];
    const float* W_embed    = (const float*)d_in[7];
    const float* Wr0        = (const float*)d_in[8];
    const float* Wr1        = (const float*)d_in[9];
    const float* Wr2        = (const float*)d_in[10];
    const float* Wmix       = (const float*)d_in[11];
    const float* Wprod      = (const float*)d_in[12];
    const float* Wread0     = (const float*)d_in[13];
    const float* Wm1        = (const float*)d_in[14];
    const float* wm2        = (const float*)d_in[15];
    // d_in[16] Wq: unused

    int N = in_sizes[0] / 3;
    int E = in_sizes[4] / 2;
    float* out = (float*)d_out;

    char* ws = (char*)d_ws;
    size_t off = 0;
    float4* geo   = (float4*)(ws + off); off += (size_t)E * sizeof(float4);
    float4* geoS  = (float4*)(ws + off); off += (size_t)E * sizeof(float4);
    float*  S0    = (float*)(ws + off);  off += (size_t)N * F * sizeof(float);
    float*  S1    = (float*)(ws + off);  off += (size_t)N * F * sizeof(float);
    int*    esrc  = (int*)(ws + off);    off += (size_t)E * sizeof(int);
    int*    edst  = (int*)(ws + off);    off += (size_t)E * sizeof(int);
    int*    srcS  = (int*)(ws + off);    off += (size_t)E * sizeof(int);
    int*    deg   = (int*)(ws + off);    off += (size_t)N * sizeof(int);
    int*    start = (int*)(ws + off);    off += (size_t)N * sizeof(int);
    int*    cursor= (int*)(ws + off);    off += (size_t)N * sizeof(int);
    float*  epart = (float*)(ws + off);  off += GSEG * EPW * sizeof(float);
    int*    count = (int*)(ws + off);    off += 128;
    int*    total = (int*)(ws + off);    off += 128;

    hipMemsetAsync(deg, 0, (size_t)N * sizeof(int), stream);
    hipMemsetAsync(epart, 0, GSEG * EPW * sizeof(float) + 256, stream); // + count/total

    int nodeBlocks4 = (N + 3) / 4;
    int nodeBlocks256 = (N + 255) / 256;
    int edgeBlocks = (E + 255) / 256;
    int gatherBlocks = (N + 7) / 8;

    init_nodes<<<nodeBlocks4, 256, 0, stream>>>(node_attrs, AE, W_embed, batch, S0, epart, N);
    edge_prep<<<edgeBlocks, 256, 0, stream>>>(positions, shifts, edge_index, E,
                                              count, geo, esrc, edst, deg);
    alloc_start<<<nodeBlocks256, 256, 0, stream>>>(deg, start, cursor, total, N);
    csr_fill<<<edgeBlocks, 256, 0, stream>>>(count, geo, esrc, edst, cursor, geoS, srcS);

    // t = 0: read S0, write S1
    gather_node<0><<<gatherBlocks, 512, 0, stream>>>(geoS, srcS, start, deg,
                                         Wr0, Wr1, Wr2, Wmix, Wprod,
                                         node_attrs, batch, Wread0, Wm1, wm2,
                                         S0, S1, epart, N);
    // t = 1: read S1 (messages + residual), no Sout written
    gather_node<1><<<gatherBlocks, 512, 0, stream>>>(geoS, srcS, start, deg,
                                         Wr0 + 512, Wr1 + 4096, Wr2 + 12288,
                                         Wmix + 12288, Wprod + NE * F * 3,
                                         node_attrs, batch, Wread0, Wm1, wm2,
                                         S1, S1, epart, N);

    reduce_energy<<<1, 256, 0, stream>>>(epart, out);
}

// Round 6
// 500.282 us; speedup vs baseline: 3.2119x; 1.7167x over previous
//
#include <hip/hip_runtime.h>
#include <hip/hip_bf16.h>

#define F 64
#define NB 8
#define NE 10
#define GSEG 4
#define EPW 256   // energy-partial spread width (contention relief)

__device__ __forceinline__ float silu(float x) {
    return x / (1.0f + __expf(-x));
}

// wave broadcast: v_readlane -> SGPR, feeds FMA as scalar operand
__device__ __forceinline__ float bcast(float v, int lane) {
    return __uint_as_float(__builtin_amdgcn_readlane(__float_as_uint(v), lane));
}

// ---------------------------------------------------------------------------
// Kernel 1: per-node init. S0[n][g] = attrs[n] @ W_embed; e0 -> epart.
// ---------------------------------------------------------------------------
__global__ __launch_bounds__(256) void init_nodes(
    const float* __restrict__ node_attrs, const float* __restrict__ AE,
    const float* __restrict__ W_embed, const int* __restrict__ batch,
    float* __restrict__ S0, float* __restrict__ epart, int N)
{
    int w = threadIdx.x >> 6, g = threadIdx.x & 63;
    int n = blockIdx.x * 4 + w;
    if (n >= N) return;
    float sc = 0.0f, e0 = 0.0f;
    #pragma unroll
    for (int e = 0; e < NE; e++) {
        float a = node_attrs[n * NE + e];
        sc = fmaf(a, W_embed[e * F + g], sc);
        e0 = fmaf(a, AE[e], e0);
    }
    S0[(size_t)n * F + g] = sc;
    if (g == 0) atomicAdd(&epart[batch[n] * EPW + (n & (EPW - 1))], e0);
}

// ---------------------------------------------------------------------------
// Kernel 2: edge compaction (r < R_MAX) + per-dst degree count.
// ---------------------------------------------------------------------------
__global__ __launch_bounds__(256) void edge_prep(
    const float* __restrict__ pos, const float* __restrict__ shifts,
    const int* __restrict__ EI, int E,
    int* __restrict__ count, float4* __restrict__ geo,
    int* __restrict__ esrc, int* __restrict__ edst, int* __restrict__ deg)
{
    int e = blockIdx.x * 256 + threadIdx.x;
    if (e >= E) return;
    int s = EI[e], d = EI[E + e];
    float vx = pos[d * 3 + 0] - pos[s * 3 + 0] + shifts[e * 3 + 0];
    float vy = pos[d * 3 + 1] - pos[s * 3 + 1] + shifts[e * 3 + 1];
    float vz = pos[d * 3 + 2] - pos[s * 3 + 2] + shifts[e * 3 + 2];
    float len = sqrtf(vx * vx + vy * vy + vz * vz);
    if (len < 5.0f) {
        float ls = (len > 1e-6f) ? len : 1.0f;
        float inv = 1.0f / ls;
        int idx = atomicAdd(count, 1);   // compiler wave-aggregates
        geo[idx] = make_float4(vx * inv, vy * inv, vz * inv, len);
        esrc[idx] = s;
        edst[idx] = d;
        atomicAdd(&deg[d], 1);
    }
}

// ---------------------------------------------------------------------------
// Kernel 3: allocate contiguous CSR ranges (order across nodes irrelevant).
// ---------------------------------------------------------------------------
__global__ __launch_bounds__(256) void alloc_start(
    const int* __restrict__ deg, int* __restrict__ start,
    int* __restrict__ cursor, int* __restrict__ total, int N)
{
    int n = blockIdx.x * 256 + threadIdx.x;
    if (n >= N) return;
    int st = atomicAdd(total, deg[n]);
    start[n] = st;
    cursor[n] = st;
}

// ---------------------------------------------------------------------------
// Kernel 4: place geometry + src id DIRECTLY into CSR slots.
// ---------------------------------------------------------------------------
__global__ __launch_bounds__(256) void csr_fill(
    const int* __restrict__ count, const float4* __restrict__ geo,
    const int* __restrict__ esrc, const int* __restrict__ edst,
    int* __restrict__ cursor,
    float4* __restrict__ geoS, int* __restrict__ srcS)
{
    int i = blockIdx.x * 256 + threadIdx.x;
    if (i >= *count) return;
    int p = atomicAdd(&cursor[edst[i]], 1);
    geoS[p] = geo[i];
    srcS[p] = esrc[i];
}

// ---------------------------------------------------------------------------
// Kernel 5: fused per-node gather. Block = 512 = 8 waves = 8 nodes.
// Wr1 (16 KB) + Wr2 c-major (48 KB) in LDS; cross-lane via v_readlane.
// Unrolls capped (8 / 4): full unroll let the scheduler keep ~60 loads in
// flight -> ~156 VGPR demand vs the 128-reg occupancy cap -> scratch spill
// (rounds 4/5: 190 MB HBM writes/dispatch). Capped unroll ~= 110 VGPR.
// PHASE 0: write Sout, energy += sc0 @ Wread0
// PHASE 1: residual, energy += silu(sc @ Wm1) @ wm2
// ---------------------------------------------------------------------------
template <int PHASE>
__global__ __launch_bounds__(512) void gather_node(
    const float4* __restrict__ geoS, const int* __restrict__ srcS,
    const int* __restrict__ start, const int* __restrict__ deg,
    const float* __restrict__ Wr0t, const float* __restrict__ Wr1t,
    const float* __restrict__ Wr2t, const float* __restrict__ Wmixt,
    const float* __restrict__ Wprodt,
    const float* __restrict__ node_attrs, const int* __restrict__ batch,
    const float* __restrict__ Wread0, const float* __restrict__ Wm1,
    const float* __restrict__ wm2,
    const float* __restrict__ Sin, float* __restrict__ Sout,
    float* __restrict__ epart, int N)
{
    __shared__ float Wr1s[4096];    // 16 KB, [k][g]
    __shared__ float Wr2s[12288];   // 48 KB, c-major: [c][k][g]

    int t = threadIdx.x;
    for (int i = t; i < 4096; i += 512)  Wr1s[i] = Wr1t[i];
    for (int i = t; i < 12288; i += 512) {
        int k = i / 192, rem = i - k * 192;
        int gg = rem / 3, c = rem - gg * 3;
        Wr2s[c * 4096 + k * 64 + gg] = Wr2t[i];
    }
    __syncthreads();   // only block-wide barrier; before any divergence

    int g = t & 63;
    int n = blockIdx.x * 8 + (t >> 6);
    if (n >= N) return;

    int st = start[n], dg = deg[n];
    float am0 = 0.f, am1 = 0.f, am2_ = 0.f, am3 = 0.f, am4 = 0.f,
          am5 = 0.f, am6 = 0.f, am7 = 0.f, am8 = 0.f;

    for (int i = 0; i < dg; i++) {
        float4 gv = geoS[st + i];    // sequential, no indirection
        int srcn = srcS[st + i];
        float sv = Sin[(size_t)srcn * F + g];   // overlap with MLP chain
        float ux = gv.x, uy = gv.y, uz = gv.z, r = gv.w;

        // radial embedding
        float rs = fmaxf(r, 1e-6f);
        float s1, c1;
        __sincosf(0.6283185307179586f * rs, &s1, &c1);   // pi*r/5
        float u = r * 0.2f;
        float u2 = u * u, u4 = u2 * u2, u5 = u4 * u, u6 = u5 * u, u7 = u6 * u;
        float fc = 1.0f - 21.0f * u5 + 35.0f * u6 - 15.0f * u7;
        float pref = 0.6324555320336759f / rs * fc;      // sqrt(2/5)
        float ef[NB];
        {
            float sp = 0.0f, sc_ = s1, tc = 2.0f * c1;
            #pragma unroll
            for (int k = 0; k < NB; k++) {
                ef[k] = pref * sc_;
                float sn = tc * sc_ - sp;
                sp = sc_; sc_ = sn;
            }
        }

        // layer 1: 8 -> 64 (Wr0 is 2 KB, L1-hot)
        float a1 = 0.0f;
        #pragma unroll
        for (int k = 0; k < NB; k++) a1 = fmaf(ef[k], Wr0t[k * 64 + g], a1);
        float h1 = silu(a1);

        // layer 2: 64 -> 64, h1 broadcast via readlane, weights from LDS
        float a2 = 0.0f;
        #pragma unroll 8
        for (int k = 0; k < 64; k++)
            a2 = fmaf(bcast(h1, k), Wr1s[k * 64 + g], a2);
        float h2 = silu(a2);

        // layer 3: 64 -> 192, c-major planes; stride-64 lane-consecutive reads
        float w0 = 0.f, w1 = 0.f, w2 = 0.f;
        #pragma unroll 8
        for (int k = 0; k < 64; k++) {
            float hk = bcast(h2, k);
            int a = k * 64 + g;
            w0 = fmaf(hk, Wr2s[a], w0);
            w1 = fmaf(hk, Wr2s[4096 + a], w1);
            w2 = fmaf(hk, Wr2s[8192 + a], w2);
        }

        // message accumulate (registers only)
        float m0 = w0 * sv, m1 = w1 * sv, m2 = w2 * sv;
        const float s3 = 1.7320508075688772f;
        const float s5h = 1.1180339887498948f;
        const float s15 = 3.8729833462074170f;
        const float s15h = 1.9364916731037085f;
        am0 += m0;
        am1 = fmaf(m1, s3 * ux, am1);
        am2_ = fmaf(m1, s3 * uy, am2_);
        am3 = fmaf(m1, s3 * uz, am3);
        am4 = fmaf(m2, s15 * ux * uy, am4);
        am5 = fmaf(m2, s15 * uy * uz, am5);
        am6 = fmaf(m2, s5h * (3.0f * uz * uz - 1.0f), am6);
        am7 = fmaf(m2, s15 * ux * uz, am7);
        am8 = fmaf(m2, s15h * (ux * ux - uy * uy), am8);
    }

    const float inv16 = 0.0625f;   // / AVG_NEIGH
    am0 *= inv16; am1 *= inv16; am2_ *= inv16; am3 *= inv16; am4 *= inv16;
    am5 *= inv16; am6 *= inv16; am7 *= inv16; am8 *= inv16;

    // mixing: b[g][s] = sum_f A[f][s] * Wmix[l(s)][f][g] — readlane transpose
    float b0 = 0.f, b1 = 0.f, b2 = 0.f, b3 = 0.f, b4 = 0.f,
          b5 = 0.f, b6 = 0.f, b7 = 0.f, b8 = 0.f;
    #pragma unroll 4
    for (int f = 0; f < 64; f++) {
        float w0 = Wmixt[f * 64 + g];
        float w1 = Wmixt[4096 + f * 64 + g];
        float w2 = Wmixt[8192 + f * 64 + g];
        b0 = fmaf(bcast(am0, f), w0, b0);
        b1 = fmaf(bcast(am1, f), w1, b1);
        b2 = fmaf(bcast(am2_, f), w1, b2);
        b3 = fmaf(bcast(am3, f), w1, b3);
        b4 = fmaf(bcast(am4, f), w2, b4);
        b5 = fmaf(bcast(am5, f), w2, b5);
        b6 = fmaf(bcast(am6, f), w2, b6);
        b7 = fmaf(bcast(am7, f), w2, b7);
        b8 = fmaf(bcast(am8, f), w2, b8);
    }

    // species-conditioned polynomial scale
    float wp0 = 0.f, wp1 = 0.f, wp2 = 0.f;
    #pragma unroll
    for (int e = 0; e < NE; e++) {
        float a = node_attrs[n * NE + e];
        const float* W = Wprodt + (e * F + g) * 3;
        wp0 = fmaf(a, W[0], wp0);
        wp1 = fmaf(a, W[1], wp1);
        wp2 = fmaf(a, W[2], wp2);
    }
    float p1 = b0;
    float p2 = b0 * b0 + b1 * b1 + b2 * b2 + b3 * b3 + b4 * b4 +
               b5 * b5 + b6 * b6 + b7 * b7 + b8 * b8;
    float scale = wp0 + wp1 * p1 + wp2 * p2;
    float sc0 = b0 * scale;
    int b = batch[n];

    if (PHASE == 0) {
        Sout[(size_t)n * F + g] = sc0;
        float v = sc0 * Wread0[g];
        #pragma unroll
        for (int off = 32; off > 0; off >>= 1) v += __shfl_xor(v, off);
        if (g == 0) atomicAdd(&epart[b * EPW + (n & (EPW - 1))], v);
    } else {
        sc0 += Sin[(size_t)n * F + g];   // residual (prev channel-0)
        // readout: silu(sc @ Wm1) @ wm2 — readlane transpose, no LDS
        int gi = g & 15;
        float acc = 0.0f;
        #pragma unroll 8
        for (int k = 0; k < 64; k++)
            acc = fmaf(bcast(sc0, k), Wm1[k * 16 + gi], acc);
        float v = (g < 16) ? silu(acc) * wm2[gi] : 0.0f;
        #pragma unroll
        for (int off = 32; off > 0; off >>= 1) v += __shfl_xor(v, off);
        if (g == 0) atomicAdd(&epart[b * EPW + (n & (EPW - 1))], v);
    }
}

// ---------------------------------------------------------------------------
// Kernel 6: final energy reduction; sole writer of d_out.
// ---------------------------------------------------------------------------
__global__ __launch_bounds__(256) void reduce_energy(
    const float* __restrict__ epart, float* __restrict__ out)
{
    int t = threadIdx.x;
    __shared__ float ps[GSEG][4];
    for (int b = 0; b < GSEG; b++) {
        float v = epart[b * EPW + t];
        #pragma unroll
        for (int off = 32; off > 0; off >>= 1) v += __shfl_xor(v, off);
        if ((t & 63) == 0) ps[b][t >> 6] = v;
    }
    __syncthreads();
    if (t < GSEG) out[t] = ps[t][0] + ps[t][1] + ps[t][2] + ps[t][3];
}

extern "C" void kernel_launch(void* const* d_in, const int* in_sizes, int n_in,
                              void* d_out, int out_size, void* d_ws, size_t ws_size,
                              hipStream_t stream) {
    const float* positions  = (const float*)d_in[0];
    const float* node_attrs = (const float*)d_in[1];
    const float* shifts     = (const float*)d_in[2];
    // d_in[3] charges: unused (charge_density never feeds energy)
    const int*   edge_index = (const int*)d_in[4];
    const int*   batch      = (const int*)d_in[5];
    const float* AE         = (const float*)d_in[6];
    const float* W_embed    = (const float*)d_in[7];
    const float* Wr0        = (const float*)d_in[8];
    const float* Wr1        = (const float*)d_in[9];
    const float* Wr2        = (const float*)d_in[10];
    const float* Wmix       = (const float*)d_in[11];
    const float* Wprod      = (const float*)d_in[12];
    const float* Wread0     = (const float*)d_in[13];
    const float* Wm1        = (const float*)d_in[14];
    const float* wm2        = (const float*)d_in[15];
    // d_in[16] Wq: unused

    int N = in_sizes[0] / 3;
    int E = in_sizes[4] / 2;
    float* out = (float*)d_out;

    char* ws = (char*)d_ws;
    size_t off = 0;
    float4* geo   = (float4*)(ws + off); off += (size_t)E * sizeof(float4);
    float4* geoS  = (float4*)(ws + off); off += (size_t)E * sizeof(float4);
    float*  S0    = (float*)(ws + off);  off += (size_t)N * F * sizeof(float);
    float*  S1    = (float*)(ws + off);  off += (size_t)N * F * sizeof(float);
    int*    esrc  = (int*)(ws + off);    off += (size_t)E * sizeof(int);
    int*    edst  = (int*)(ws + off);    off += (size_t)E * sizeof(int);
    int*    srcS  = (int*)(ws + off);    off += (size_t)E * sizeof(int);
    int*    deg   = (int*)(ws + off);    off += (size_t)N * sizeof(int);
    int*    start = (int*)(ws + off);    off += (size_t)N * sizeof(int);
    int*    cursor= (int*)(ws + off);    off += (size_t)N * sizeof(int);
    float*  epart = (float*)(ws + off);  off += GSEG * EPW * sizeof(float);
    int*    count = (int*)(ws + off);    off += 128;
    int*    total = (int*)(ws + off);    off += 128;

    hipMemsetAsync(deg, 0, (size_t)N * sizeof(int), stream);
    hipMemsetAsync(epart, 0, GSEG * EPW * sizeof(float) + 256, stream); // + count/total

    int nodeBlocks4 = (N + 3) / 4;
    int nodeBlocks256 = (N + 255) / 256;
    int edgeBlocks = (E + 255) / 256;
    int gatherBlocks = (N + 7) / 8;

    init_nodes<<<nodeBlocks4, 256, 0, stream>>>(node_attrs, AE, W_embed, batch, S0, epart, N);
    edge_prep<<<edgeBlocks, 256, 0, stream>>>(positions, shifts, edge_index, E,
                                              count, geo, esrc, edst, deg);
    alloc_start<<<nodeBlocks256, 256, 0, stream>>>(deg, start, cursor, total, N);
    csr_fill<<<edgeBlocks, 256, 0, stream>>>(count, geo, esrc, edst, cursor, geoS, srcS);

    // t = 0: read S0, write S1
    gather_node<0><<<gatherBlocks, 512, 0, stream>>>(geoS, srcS, start, deg,
                                         Wr0, Wr1, Wr2, Wmix, Wprod,
                                         node_attrs, batch, Wread0, Wm1, wm2,
                                         S0, S1, epart, N);
    // t = 1: read S1 (messages + residual), no Sout written
    gather_node<1><<<gatherBlocks, 512, 0, stream>>>(geoS, srcS, start, deg,
                                         Wr0 + 512, Wr1 + 4096, Wr2 + 12288,
                                         Wmix + 12288, Wprod + NE * F * 3,
                                         node_attrs, batch, Wread0, Wm1, wm2,
                                         S1, S1, epart, N);

    reduce_energy<<<1, 256, 0, stream>>>(epart, out);
}